// Round 3
// baseline (572.640 us; speedup 1.0000x reference)
//
#include <hip/hip_runtime.h>
#include <math.h>

#define IN_CH    256
#define HIDDEN   8
#define NBASIS   8
#define OUT_CH   2
#define HWD      25600          // 160*160
#define BATCH    16
#define PXB      256            // pixels per block (one 1 KiB row per channel)
#define CH_CHUNK 8              // channels staged per chunk
#define NCHUNK   (IN_CH / CH_CHUNK)   // 32

// Streaming structure (m97 pattern): double-buffered LDS x-tiles staged with
// global_load_lds width=16 (1 instr = 1 wave = one 256-px channel row).
// Per chunk: issue next tile's 8 rows, consume current tile (8 ch x 8 FMA
// per thread), __syncthreads (implicit vmcnt drain). 1600 blocks, 6/CU
// resident (LDS-bound), phase-staggered blocks keep ~48 KB/CU in flight.
__global__ __launch_bounds__(256) void rbf_fused_kernel(
    const float* __restrict__ x,
    const float* __restrict__ conv_w,      // [HIDDEN][IN_CH]
    const float* __restrict__ conv_b,      // [HIDDEN]
    const float* __restrict__ centers,     // [HIDDEN*NBASIS]
    const float* __restrict__ log_widths,  // [HIDDEN*NBASIS]
    const float* __restrict__ out_w,       // [OUT_CH][HIDDEN][NBASIS]
    const float* __restrict__ out_bias,    // [OUT_CH]
    float* __restrict__ out)               // [BATCH][OUT_CH][HWD]
{
    __shared__ float tile[2][CH_CHUNK][PXB];    // 16 KiB double buffer
    __shared__ float s_w[IN_CH][HIDDEN];        // 8 KiB transposed conv_w
    __shared__ float s_cen[HIDDEN * NBASIS];
    __shared__ float s_iw[HIDDEN * NBASIS];
    __shared__ float s_ow0[HIDDEN * NBASIS];
    __shared__ float s_ow1[HIDDEN * NBASIS];
    __shared__ float s_cb[HIDDEN];
    __shared__ float s_ob[OUT_CH];

    const int tid  = threadIdx.x;
    const int wv   = tid >> 6;        // wave 0..3
    const int lane = tid & 63;

    for (int i = tid; i < IN_CH * HIDDEN; i += 256) {
        const int c = i >> 3, k = i & 7;
        s_w[c][k] = conv_w[k * IN_CH + c];
    }
    if (tid < HIDDEN * NBASIS) {
        s_cen[tid] = centers[tid];
        const float wdt = log1pf(__expf(log_widths[tid])) + 0.001f;  // softplus+eps
        s_iw[tid]  = 1.0f / wdt;
        s_ow0[tid] = out_w[tid];
        s_ow1[tid] = out_w[HIDDEN * NBASIS + tid];
    }
    if (tid < HIDDEN) s_cb[tid] = conv_b[tid];
    if (tid < OUT_CH) s_ob[tid] = out_bias[tid];

    const int img = blockIdx.x / (HWD / PXB);   // 100 blocks per image
    const int hw0 = (blockIdx.x % (HWD / PXB)) * PXB;
    const float* xbase = x + img * (IN_CH * HWD) + hw0;  // max idx ~105M: int-safe

    // Stage one 8-channel chunk: each wave DMAs 2 rows (1 KiB each) to LDS.
    auto stage = [&](int cc, int bf) {
        const int c0 = cc * CH_CHUNK;
        #pragma unroll
        for (int rr = 0; rr < 2; ++rr) {
            const int r = wv + rr * 4;
            const float* gp = xbase + (c0 + r) * HWD + lane * 4;
            __builtin_amdgcn_global_load_lds(
                (const __attribute__((address_space(1))) void*)gp,
                (__attribute__((address_space(3))) void*)&tile[bf][r][0],
                16, 0, 0);
        }
    };

    float acc[HIDDEN];

    stage(0, 0);
    __syncthreads();   // drains vmcnt(0): chunk 0 landed; weights staged

    #pragma unroll
    for (int k = 0; k < HIDDEN; ++k) acc[k] = s_cb[k];

    int bf = 0;
    for (int cc = 0; cc < NCHUNK; ++cc) {
        if (cc + 1 < NCHUNK) stage(cc + 1, bf ^ 1);   // issue-early: overlaps consume
        const int c0 = cc * CH_CHUNK;
        #pragma unroll
        for (int r = 0; r < CH_CHUNK; ++r) {
            const float xv = tile[bf][r][tid];
            const int c = c0 + r;
            const float4 wlo = *reinterpret_cast<const float4*>(&s_w[c][0]);
            const float4 whi = *reinterpret_cast<const float4*>(&s_w[c][4]);
            acc[0] = fmaf(xv, wlo.x, acc[0]);
            acc[1] = fmaf(xv, wlo.y, acc[1]);
            acc[2] = fmaf(xv, wlo.z, acc[2]);
            acc[3] = fmaf(xv, wlo.w, acc[3]);
            acc[4] = fmaf(xv, whi.x, acc[4]);
            acc[5] = fmaf(xv, whi.y, acc[5]);
            acc[6] = fmaf(xv, whi.z, acc[6]);
            acc[7] = fmaf(xv, whi.w, acc[7]);
        }
        __syncthreads();   // implicit vmcnt(0)+lgkmcnt(0): next tile landed, cur consumed
        bf ^= 1;
    }

    // Epilogue: phi = exp(-((z-cen)*iw)^2); 2-channel head.
    float o0 = s_ob[0], o1 = s_ob[1];
    #pragma unroll
    for (int k = 0; k < HIDDEN; ++k) {
        const float z = acc[k];
        #pragma unroll
        for (int j = 0; j < NBASIS; ++j) {
            const int kj = k * NBASIS + j;
            const float t   = (z - s_cen[kj]) * s_iw[kj];
            const float phi = __expf(-t * t);
            o0 = fmaf(phi, s_ow0[kj], o0);
            o1 = fmaf(phi, s_ow1[kj], o1);
        }
    }

    out[(img * OUT_CH + 0) * HWD + hw0 + tid] = o0;
    out[(img * OUT_CH + 1) * HWD + hw0 + tid] = o1;
}

extern "C" void kernel_launch(void* const* d_in, const int* in_sizes, int n_in,
                              void* d_out, int out_size, void* d_ws, size_t ws_size,
                              hipStream_t stream) {
    const float* x          = (const float*)d_in[0];
    const float* conv_w     = (const float*)d_in[1];
    const float* conv_b     = (const float*)d_in[2];
    const float* centers    = (const float*)d_in[3];
    const float* log_widths = (const float*)d_in[4];
    const float* out_w      = (const float*)d_in[5];
    const float* out_bias   = (const float*)d_in[6];
    float* out = (float*)d_out;

    const int blocks = BATCH * (HWD / PXB);   // 1600
    rbf_fused_kernel<<<blocks, 256, 0, stream>>>(
        x, conv_w, conv_b, centers, log_widths, out_w, out_bias, out);
}